// Round 5
// baseline (81.227 us; speedup 1.0000x reference)
//
#include <hip/hip_runtime.h>
#include <math.h>

#define BATCH 128
#define NPWM 512
#define LEN 1000
#define KSZ 19
#define NPOS 982
#define NEXT 1024     // 2*NPWM (fwd + revcomp interleaved: f_ext = 2*f + strand)
#define KSLOT 80      // kk padded 19->20, slot = kk*4 + c  (32x32x16 needs K % 16 == 0)

typedef __bf16 bf16x4 __attribute__((ext_vector_type(4)));
typedef __bf16 bf16x8 __attribute__((ext_vector_type(8)));
typedef float  f32x16 __attribute__((ext_vector_type(16)));

#define MFMA32(a, b, c) __builtin_amdgcn_mfma_f32_32x32x16_bf16(a, b, c, 0, 0, 0)

// ---- prepack W: (512,4,19) fp32 -> (1024,80) bf16 hi/lo, zeros at pad slots ----
__global__ __launch_bounds__(256)
void prepack_w(const float* __restrict__ w, __bf16* __restrict__ whi, __bf16* __restrict__ wlo)
{
    int idx = blockIdx.x * 256 + threadIdx.x;
    if (idx >= NEXT * KSLOT) return;
    int fe = idx / KSLOT;
    int t  = idx - fe * KSLOT;
    int kk = t >> 2;
    int c  = t & 3;
    int f      = fe >> 1;
    int strand = fe & 1;
    float v = 0.0f;
    if (kk < KSZ)
        v = strand ? w[f*76 + (3-c)*19 + (18-kk)]   // reverse-complement
                   : w[f*76 + c*19 + kk];
    __bf16 h = (__bf16)v;
    whi[idx] = h;
    wlo[idx] = (__bf16)(v - (float)h);
}

// ---- main: im2col bf16-split GEMM, 32x32x16 MFMA, fused position-max ----
// block = 4 waves = 2 filter-halves x 2 position-halves; wave: 64 f_ext, ~15.5 iters.
// grid = (128, 8) = 1024 blocks = 4/CU -> 4 waves/SIMD (VGPR 84 fits).
__global__ __launch_bounds__(256, 4)
void pwm_mfma(const float* __restrict__ x,
              const __bf16* __restrict__ whi,
              const __bf16* __restrict__ wlo,
              float* __restrict__ out)
{
    __shared__ __align__(16) __bf16 H[4096];   // x hi, [pos][c], pos 0..1023 (tail 0)
    __shared__ __align__(16) __bf16 L[4096];   // x lo
    __shared__ float red[2][128];

    const int tid   = threadIdx.x;
    const int b     = blockIdx.x;
    const int ftile = blockIdx.y;   // 0..7 (128 f_ext per block)
    const int lane  = tid & 63;
    const int wave  = tid >> 6;
    const int fhalf = wave & 1;     // which 64 f_ext
    const int wp    = wave >> 1;    // which position half
    const int col   = lane & 31;    // A-row / B-col / D-col index
    const int gh    = lane >> 5;    // k-group half

    // stage x[b] -> bf16 hi/lo, position-major [pos][channel]; 8B LDS writes
    for (int i = tid; i < 1024; i += 256) {
        bf16x4 hv, lv;
        #pragma unroll
        for (int c = 0; c < 4; ++c) {
            float v = (i < LEN) ? x[(size_t)b*4000 + c*1000 + i] : 0.0f;
            __bf16 h = (__bf16)v;
            hv[c] = h;
            lv[c] = (__bf16)(v - (float)h);
        }
        *(bf16x4*)(H + i*4) = hv;
        *(bf16x4*)(L + i*4) = lv;
    }

    // A fragments (W) -> regs: lane holds W[f0+fg*32+col][k = t*16 + gh*8 + j]
    bf16x8 wah[2][5], wal[2][5];
    {
        const int f0 = ftile*128 + fhalf*64;
        #pragma unroll
        for (int fg = 0; fg < 2; ++fg)
            #pragma unroll
            for (int t = 0; t < 5; ++t) {
                const size_t o = (size_t)(f0 + fg*32 + col)*KSLOT + t*16 + gh*8;
                wah[fg][t] = *(const bf16x8*)(whi + o);
                wal[fg][t] = *(const bf16x8*)(wlo + o);
            }
    }
    __syncthreads();

    f32x16 m0, m1;
    #pragma unroll
    for (int r = 0; r < 16; ++r) { m0[r] = -INFINITY; m1[r] = -INFINITY; }

    // one K-sweep for 32 positions starting at it*32; merge into m0/m1
    auto body = [&](int it, bool tail) {
        f32x16 a0 = {}, a1 = {};
        const int ebase = it*128 + (col + 2*gh)*4;
        #pragma unroll
        for (int t = 0; t < 5; ++t) {
            const __bf16* pH = H + ebase + t*16;
            const __bf16* pL = L + ebase + t*16;
            bf16x4 h0 = *(const bf16x4*)(pH);
            bf16x4 h1 = *(const bf16x4*)(pH + 4);
            bf16x4 l0 = *(const bf16x4*)(pL);
            bf16x4 l1 = *(const bf16x4*)(pL + 4);
            bf16x8 bh = __builtin_shufflevector(h0, h1, 0,1,2,3,4,5,6,7);
            bf16x8 bl = __builtin_shufflevector(l0, l1, 0,1,2,3,4,5,6,7);
            a0 = MFMA32(wah[0][t], bh, a0);
            a1 = MFMA32(wah[1][t], bh, a1);
            a0 = MFMA32(wal[0][t], bh, a0);
            a1 = MFMA32(wal[1][t], bh, a1);
            a0 = MFMA32(wah[0][t], bl, a0);
            a1 = MFMA32(wah[1][t], bl, a1);
        }
        if (!tail || col < 22) {   // mask pos >= 982 (it==30: pos = 960+col)
            #pragma unroll
            for (int r = 0; r < 16; ++r) {
                m0[r] = fmaxf(m0[r], a0[r]);
                m1[r] = fmaxf(m1[r], a1[r]);
            }
        }
    };

    if (wp == 0) {
        for (int it = 0; it < 16; ++it) body(it, false);
    } else {
        for (int it = 16; it < 30; ++it) body(it, false);
        body(30, true);
    }

    // reduce over the 32 position-columns (within each 32-lane half)
    #pragma unroll
    for (int off = 1; off <= 16; off <<= 1) {
        #pragma unroll
        for (int r = 0; r < 16; ++r) {
            m0[r] = fmaxf(m0[r], __shfl_xor(m0[r], off, 64));
            m1[r] = fmaxf(m1[r], __shfl_xor(m1[r], off, 64));
        }
    }

    // D row (filter within 32-tile) = (r&3) + 8*(r>>2) + 4*gh
    if (col == 0) {
        #pragma unroll
        for (int r = 0; r < 16; ++r) {
            const int row = (r & 3) + 8*(r >> 2) + 4*gh;
            red[wp][fhalf*64 + row]      = m0[r];
            red[wp][fhalf*64 + 32 + row] = m1[r];
        }
    }
    __syncthreads();
    if (tid < 64) {   // combine strand pairs (f_ext = 2f, 2f+1) and position halves
        const int base = 2*tid;
        float v0 = fmaxf(red[0][base], red[0][base+1]);
        float v1 = fmaxf(red[1][base], red[1][base+1]);
        out[(size_t)b*NPWM + ftile*64 + tid] = fmaxf(v0, v1);
    }
}

extern "C" void kernel_launch(void* const* d_in, const int* in_sizes, int n_in,
                              void* d_out, int out_size, void* d_ws, size_t ws_size,
                              hipStream_t stream)
{
    const float* x = (const float*)d_in[0];   // (128, 4, 1000)
    const float* w = (const float*)d_in[1];   // (512, 4, 19)
    float* out = (float*)d_out;               // (128, 512)

    __bf16* whi = (__bf16*)d_ws;              // 1024*80 bf16
    __bf16* wlo = whi + NEXT*KSLOT;

    prepack_w<<<dim3((NEXT*KSLOT + 255)/256), 256, 0, stream>>>(w, whi, wlo);
    pwm_mfma<<<dim3(BATCH, 8), 256, 0, stream>>>(x, whi, wlo, out);
}

// Round 6
// 44.893 us; speedup vs baseline: 1.8094x; 1.8094x over previous
//
#include <hip/hip_runtime.h>
#include <math.h>

#define BATCH 128
#define NPWM 512
#define LEN 1000
#define NPOS 982
#define NEXT 1024     // 2*NPWM (fwd + revcomp interleaved: f_ext = 2*f + strand)
#define KSLOT 80      // kk padded 19->20, slot = kk*4 + c

typedef __bf16 bf16x4 __attribute__((ext_vector_type(4)));
typedef __bf16 bf16x8 __attribute__((ext_vector_type(8)));
typedef float  f32x16 __attribute__((ext_vector_type(16)));

#define MFMA32(a, b, c) __builtin_amdgcn_mfma_f32_32x32x16_bf16(a, b, c, 0, 0, 0)

// ---- prepack W: (512,4,19) fp32 -> (1024,80) bf16 hi/lo, zeros at pad slots ----
__global__ __launch_bounds__(256)
void prepack_w(const float* __restrict__ w, __bf16* __restrict__ whi, __bf16* __restrict__ wlo)
{
    int idx = blockIdx.x * 256 + threadIdx.x;
    if (idx >= NEXT * KSLOT) return;
    int fe = idx / KSLOT;
    int t  = idx - fe * KSLOT;
    int kk = t >> 2;
    int c  = t & 3;
    int f      = fe >> 1;
    int strand = fe & 1;
    float v = 0.0f;
    if (kk < 19)
        v = strand ? w[f*76 + (3-c)*19 + (18-kk)]   // reverse-complement
                   : w[f*76 + c*19 + kk];
    __bf16 h = (__bf16)v;
    whi[idx] = h;
    wlo[idx] = (__bf16)(v - (float)h);
}

// one K-sweep over 32 positions starting at (IT)*32
#define KBODY(IT, MASKED)                                               \
  {                                                                     \
    f32x16 a = {};                                                      \
    const int e0 = (IT)*128 + cgh4;                                     \
    _Pragma("unroll")                                                   \
    for (int t = 0; t < 5; ++t) {                                       \
      bf16x8 bh = *(const bf16x8*)(bp + e0 + t*16);                     \
      a = MFMA32(wah[t], bh, a);                                        \
      a = MFMA32(wal[t], bh, a);                                        \
    }                                                                   \
    if (!(MASKED) || col < 22) {                                        \
      _Pragma("unroll")                                                 \
      for (int r = 0; r < 16; ++r) m[r] = fmaxf(m[r], a[r]);            \
    }                                                                   \
  }

// ---- main: 2-term w-split GEMM, 32x32x16, fg=1 per wave, fused position-max ----
// block = 4 waves = 2 filter-tiles x 2 position-halves; wave: 32 f_ext, ~15.5 iters.
// grid = (128, 16) = 2048 blocks. VGPR ~90 -> 5 waves/SIMD reg-wise.
__global__ __launch_bounds__(256, 4)
void pwm_mfma(const float* __restrict__ x,
              const __bf16* __restrict__ whi,
              const __bf16* __restrict__ wlo,
              float* __restrict__ out)
{
    __shared__ __align__(16) __bf16 H [4096];   // bf16(x), [pos][c], tail 0
    __shared__ __align__(16) __bf16 H1[4096];   // shifted +1 pos (odd-parity alignment)
    __shared__ float red[2][64];

    const int tid   = threadIdx.x;
    const int b     = blockIdx.x;
    const int by    = blockIdx.y;   // 0..15: which 64 f_ext
    const int lane  = tid & 63;
    const int wave  = tid >> 6;
    const int fhalf = wave & 1;     // which 32-filter tile
    const int wp    = wave >> 1;    // position half
    const int col   = lane & 31;
    const int gh    = lane >> 5;

    // stage bf16(x[b]) position-major + shifted copy (single pass, no extra barrier)
    for (int i = tid; i < 1024; i += 256) {
        bf16x4 hv;
        #pragma unroll
        for (int c = 0; c < 4; ++c) {
            float v = (i < LEN) ? x[(size_t)b*4000 + c*1000 + i] : 0.0f;
            hv[c] = (__bf16)v;
        }
        *(bf16x4*)(H + i*4) = hv;
        if (i > 0) *(bf16x4*)(H1 + (i-1)*4) = hv;
    }
    if (tid == 0) {
        bf16x4 z = {};
        *(bf16x4*)(H1 + 1023*4) = z;
    }

    // A fragments (W hi/lo) -> regs: lane holds W[f0+col][k = t*16 + gh*8 + j]
    bf16x8 wah[5], wal[5];
    {
        const int f0 = by*64 + fhalf*32;
        #pragma unroll
        for (int t = 0; t < 5; ++t) {
            const size_t o = (size_t)(f0 + col)*KSLOT + t*16 + gh*8;
            wah[t] = *(const bf16x8*)(whi + o);
            wal[t] = *(const bf16x8*)(wlo + o);
        }
    }
    __syncthreads();

    // B base: element (pos + kk)*4 + c with pos = it*32 + col, slots k = t*16+gh*8+j
    const int cgh4 = (col + 2*gh)*4;
    const __bf16* bp = (col & 1) ? (H1 - 4) : H;   // parity-aligned buffer (16B reads)

    f32x16 m;
    #pragma unroll
    for (int r = 0; r < 16; ++r) m[r] = -INFINITY;

    if (wp == 0) {
        for (int it = 0; it < 16; ++it) KBODY(it, false)
    } else {
        for (int it = 16; it < 30; ++it) KBODY(it, false)
        KBODY(30, true)   // pos = 960+col; mask pos >= 982
    }

    // reduce over the 32 position-columns (within each 32-lane half)
    #pragma unroll
    for (int off = 1; off <= 16; off <<= 1)
        #pragma unroll
        for (int r = 0; r < 16; ++r)
            m[r] = fmaxf(m[r], __shfl_xor(m[r], off, 64));

    // D row (f_ext within 32-tile) = (r&3) + 8*(r>>2) + 4*gh
    if (col == 0) {
        #pragma unroll
        for (int r = 0; r < 16; ++r) {
            const int row = (r & 3) + 8*(r >> 2) + 4*gh;
            red[wp][fhalf*32 + row] = m[r];
        }
    }
    __syncthreads();
    if (tid < 32) {   // combine strand pairs and position halves
        float v0 = fmaxf(red[0][2*tid], red[0][2*tid+1]);
        float v1 = fmaxf(red[1][2*tid], red[1][2*tid+1]);
        out[(size_t)b*NPWM + by*32 + tid] = fmaxf(v0, v1);
    }
}

extern "C" void kernel_launch(void* const* d_in, const int* in_sizes, int n_in,
                              void* d_out, int out_size, void* d_ws, size_t ws_size,
                              hipStream_t stream)
{
    const float* x = (const float*)d_in[0];   // (128, 4, 1000)
    const float* w = (const float*)d_in[1];   // (512, 4, 19)
    float* out = (float*)d_out;               // (128, 512)

    __bf16* whi = (__bf16*)d_ws;              // 1024*80 bf16
    __bf16* wlo = whi + NEXT*KSLOT;

    prepack_w<<<dim3((NEXT*KSLOT + 255)/256), 256, 0, stream>>>(w, whi, wlo);
    pwm_mfma<<<dim3(BATCH, 16), 256, 0, stream>>>(x, whi, wlo, out);
}